// Round 2
// baseline (2837.518 us; speedup 1.0000x reference)
//
#include <hip/hip_runtime.h>
#include <hip/hip_bf16.h>

#define NN 100000
#define NE 300000
#define NG 4096
#define EMB 256
#define NLAYERS 5

typedef unsigned short u16;
typedef unsigned int u32;

__device__ __forceinline__ float b2f(u16 u){
    union { float f; u32 i; } v; v.i = ((u32)u) << 16; return v.f;
}
__device__ __forceinline__ u16 f2b(float f){
    __hip_bfloat16 h = __float2bfloat16(f);   // round-to-nearest-even
    union { __hip_bfloat16 h; u16 u; } v; v.h = h; return v.u;
}

// ---------------- x embedding: h = x @ xW.T + xb  (bf16 out) ----------------
#define XNB 32
__global__ __launch_bounds__(256) void embed_x(const float* __restrict__ x,
        const float* __restrict__ W, const float* __restrict__ b,
        u16* __restrict__ h)
{
    __shared__ float sW[256][41];
    __shared__ float sx[XNB][40];
    int tid = threadIdx.x;
    for (int i = tid; i < 256*40; i += 256) sW[i/40][i%40] = W[i];
    int n0 = blockIdx.x * XNB;      // 100000 = 3125*32, exact
    for (int i = tid; i < XNB*40; i += 256) {
        int j = i/40, k = i%40;
        sx[j][k] = x[(size_t)(n0+j)*40 + k];
    }
    __syncthreads();
    float bb = b[tid];
    for (int j = 0; j < XNB; ++j) {
        float a = bb;
        #pragma unroll
        for (int k = 0; k < 40; ++k) a = fmaf(sW[tid][k], sx[j][k], a);
        h[(size_t)(n0+j)*EMB + tid] = f2b(a);
    }
}

// ---------------- degree ----------------
__global__ void deg_count(const int* __restrict__ row, float* __restrict__ degcnt, int E)
{
    int e = blockIdx.x*blockDim.x + threadIdx.x;
    if (e < E) atomicAdd(&degcnt[row[e]], 1.0f);
}

__global__ void deg_fin(const float* __restrict__ degcnt, float* __restrict__ dinv,
                        float* __restrict__ invdeg, int N)
{
    int n = blockIdx.x*blockDim.x + threadIdx.x;
    if (n < N) {
        float d = degcnt[n] + 1.0f;
        dinv[n]   = rsqrtf(d);
        invdeg[n] = 1.0f/d;
    }
}

// ---------------- GEMM: C[m][o] = sum_k A[m][k]*W[o][k] + bias[o] ----------------
// A bf16, W f32, C bf16. 64x64 tile, 256 threads, 4x4/thread, BK=32.
__global__ __launch_bounds__(256) void gemm_hx(const u16* __restrict__ A,
        const float* __restrict__ W, const float* __restrict__ bias,
        u16* __restrict__ C, int M)
{
    __shared__ __align__(16) float As[32][68];
    __shared__ __align__(16) float Bs[32][68];
    const int tid = threadIdx.x;
    const int tx = tid & 15;
    const int ty = tid >> 4;
    const int m0 = blockIdx.x * 64;
    const int n0 = blockIdx.y * 64;
    float acc[4][4] = {};
    for (int k0 = 0; k0 < 256; k0 += 32) {
        #pragma unroll
        for (int it = 0; it < 2; ++it) {
            int idx = tid + it*256;
            int r  = idx >> 3;          // 0..63
            int c4 = idx & 7;           // 0..7
            int gm = m0 + r;
            ushort4 va = make_ushort4(0,0,0,0);
            if (gm < M)
                va = *reinterpret_cast<const ushort4*>(&A[(size_t)gm*256 + k0 + c4*4]);
            As[c4*4+0][r] = b2f(va.x);
            As[c4*4+1][r] = b2f(va.y);
            As[c4*4+2][r] = b2f(va.z);
            As[c4*4+3][r] = b2f(va.w);
            float4 vb = *reinterpret_cast<const float4*>(&W[(size_t)(n0+r)*256 + k0 + c4*4]);
            Bs[c4*4+0][r] = vb.x;
            Bs[c4*4+1][r] = vb.y;
            Bs[c4*4+2][r] = vb.z;
            Bs[c4*4+3][r] = vb.w;
        }
        __syncthreads();
        #pragma unroll
        for (int kk = 0; kk < 32; ++kk) {
            float4 a = *reinterpret_cast<const float4*>(&As[kk][ty*4]);
            float4 b = *reinterpret_cast<const float4*>(&Bs[kk][tx*4]);
            acc[0][0] = fmaf(a.x, b.x, acc[0][0]);
            acc[0][1] = fmaf(a.x, b.y, acc[0][1]);
            acc[0][2] = fmaf(a.x, b.z, acc[0][2]);
            acc[0][3] = fmaf(a.x, b.w, acc[0][3]);
            acc[1][0] = fmaf(a.y, b.x, acc[1][0]);
            acc[1][1] = fmaf(a.y, b.y, acc[1][1]);
            acc[1][2] = fmaf(a.y, b.z, acc[1][2]);
            acc[1][3] = fmaf(a.y, b.w, acc[1][3]);
            acc[2][0] = fmaf(a.z, b.x, acc[2][0]);
            acc[2][1] = fmaf(a.z, b.y, acc[2][1]);
            acc[2][2] = fmaf(a.z, b.z, acc[2][2]);
            acc[2][3] = fmaf(a.z, b.w, acc[2][3]);
            acc[3][0] = fmaf(a.w, b.x, acc[3][0]);
            acc[3][1] = fmaf(a.w, b.y, acc[3][1]);
            acc[3][2] = fmaf(a.w, b.z, acc[3][2]);
            acc[3][3] = fmaf(a.w, b.w, acc[3][3]);
        }
        __syncthreads();
    }
    float4 bb = *reinterpret_cast<const float4*>(&bias[n0 + tx*4]);
    #pragma unroll
    for (int i = 0; i < 4; ++i) {
        int gm = m0 + ty*4 + i;
        if (gm < M) {
            ushort4 r;
            r.x = f2b(acc[i][0] + bb.x);
            r.y = f2b(acc[i][1] + bb.y);
            r.z = f2b(acc[i][2] + bb.z);
            r.w = f2b(acc[i][3] + bb.w);
            *reinterpret_cast<ushort4*>(&C[(size_t)gm*256 + n0 + tx*4]) = r;
        }
    }
}

// ---------------- message pass: agg[col] += norm * relu(hx[row] + ea) ----------------
#define EPW 8
__global__ __launch_bounds__(256) void msg_kernel(const int* __restrict__ row,
        const int* __restrict__ col, const float* __restrict__ eattr,
        const float* __restrict__ eW, const float* __restrict__ eb,
        const float* __restrict__ dinv, const u16* __restrict__ hx,
        float* __restrict__ agg, int E)
{
    __shared__ float sW[256][11];
    __shared__ float sb[256];
    for (int i = threadIdx.x; i < 2560; i += 256) sW[i/10][i%10] = eW[i];
    sb[threadIdx.x] = eb[threadIdx.x];
    __syncthreads();
    int wave = threadIdx.x >> 6;
    int lane = threadIdx.x & 63;
    int e0 = (blockIdx.x*4 + wave) * EPW;
    int e1 = min(e0 + EPW, E);
    for (int e = e0; e < e1; ++e) {
        int r = row[e], c = col[e];
        float nrm = dinv[r] * dinv[c];
        float at[10];
        #pragma unroll
        for (int k = 0; k < 10; ++k) at[k] = eattr[(size_t)e*10 + k];
        const u16* hxr = hx + (size_t)r*EMB;
        float* aggc = agg + (size_t)c*EMB;
        #pragma unroll
        for (int i = 0; i < 4; ++i) {
            int f = lane + 64*i;
            float ea = sb[f];
            #pragma unroll
            for (int k = 0; k < 10; ++k) ea = fmaf(at[k], sW[f][k], ea);
            float v = b2f(hxr[f]) + ea;
            float m = v > 0.f ? v*nrm : 0.f;   // nrm > 0 always
            atomicAdd(&aggc[f], m);
        }
    }
}

// ---------------- combine + BN stats ----------------
// t = h_in + agg + relu(hx+root)/deg; writes t (bf16) into hx, zeroes agg
__global__ __launch_bounds__(256) void combine_kernel(const u16* __restrict__ h,
        float* __restrict__ agg, u16* __restrict__ hx,
        const float* __restrict__ rootv, const float* __restrict__ invdeg,
        float* __restrict__ stats, int N)
{
    int f = threadIdx.x;
    float root = rootv[f];
    float s = 0.f, s2 = 0.f;
    for (int n = blockIdx.x; n < N; n += gridDim.x) {
        size_t idx = (size_t)n*EMB + f;
        float hv = b2f(hx[idx]) + root;
        hv = hv > 0.f ? hv : 0.f;
        float t = b2f(h[idx]) + agg[idx] + hv * invdeg[n];
        hx[idx] = f2b(t);
        agg[idx] = 0.f;
        s  += t;
        s2 += t*t;
    }
    atomicAdd(&stats[f], s);
    atomicAdd(&stats[256 + f], s2);
}

// ---------------- BN finalize ----------------
__global__ void bn_finalize(const float* __restrict__ stats,
        const float* __restrict__ gamma, const float* __restrict__ beta,
        float* __restrict__ sc, int N)
{
    int f = threadIdx.x;
    float inv = 1.0f / (float)N;
    float mean = stats[f] * inv;
    float var  = stats[256+f] * inv - mean*mean;
    float is = rsqrtf(var + 1e-5f);
    float scale = gamma[f] * is;
    sc[f] = scale;
    sc[256+f] = fmaf(-mean, scale, beta[f]);
}

// ---------------- BN apply (+optional relu), bf16 in/out, 8 elems/thread ----------------
__global__ __launch_bounds__(256) void bn_apply(const uint4* __restrict__ t,
        uint4* __restrict__ h, const float* __restrict__ sc, int n8, int doRelu)
{
    size_t i0 = (size_t)blockIdx.x*blockDim.x + threadIdx.x;
    int f = (int)((i0*8) & 255);   // stride*8 is a multiple of 256 -> fixed per thread
    float s[8], sh[8];
    #pragma unroll
    for (int j = 0; j < 8; ++j) { s[j] = sc[f+j]; sh[j] = sc[256+f+j]; }
    size_t stride = (size_t)gridDim.x*blockDim.x;
    for (size_t i = i0; i < (size_t)n8; i += stride) {
        uint4 v = t[i];
        u32 w[4] = {v.x, v.y, v.z, v.w};
        u32 o[4];
        #pragma unroll
        for (int j = 0; j < 4; ++j) {
            float lo = b2f((u16)(w[j] & 0xffffu));
            float hi = b2f((u16)(w[j] >> 16));
            lo = fmaf(lo, s[2*j],   sh[2*j]);
            hi = fmaf(hi, s[2*j+1], sh[2*j+1]);
            if (doRelu) { lo = fmaxf(lo, 0.f); hi = fmaxf(hi, 0.f); }
            o[j] = (u32)f2b(lo) | ((u32)f2b(hi) << 16);
        }
        uint4 r; r.x = o[0]; r.y = o[1]; r.z = o[2]; r.w = o[3];
        h[i] = r;
    }
}

// ---------------- mean pool over sorted batch ----------------
__global__ __launch_bounds__(256) void pool_kernel(const u16* __restrict__ h,
        const int* __restrict__ batch, float* __restrict__ psum,
        float* __restrict__ pcnt, int N)
{
    int f = threadIdx.x;
    int n0 = blockIdx.x * 256;
    int n1 = min(n0 + 256, N);
    int cur = batch[n0];
    float acc = 0.f;
    int cnt = 0;
    for (int n = n0; n < n1; ++n) {
        int g = batch[n];                 // block-uniform (sorted)
        if (g != cur) {
            atomicAdd(&psum[(size_t)cur*EMB + f], acc);
            if (f == 0) atomicAdd(&pcnt[cur], (float)cnt);
            acc = 0.f; cnt = 0; cur = g;
        }
        acc += b2f(h[(size_t)n*EMB + f]);
        ++cnt;
    }
    atomicAdd(&psum[(size_t)cur*EMB + f], acc);
    if (f == 0) atomicAdd(&pcnt[cur], (float)cnt);
}

// ---------------- fused MLP head ----------------
__global__ __launch_bounds__(128) void head_kernel(const float* __restrict__ psum,
        const float* __restrict__ pcnt,
        const float* __restrict__ p1W, const float* __restrict__ p1b,
        const float* __restrict__ p2W, const float* __restrict__ p2b,
        const float* __restrict__ p3W, const float* __restrict__ p3b,
        float* __restrict__ out)
{
    __shared__ float gs[256];
    __shared__ float h1[128];
    __shared__ float h2[128];
    __shared__ float red[2];
    int g = blockIdx.x, t = threadIdx.x;
    float invc = 1.0f / fmaxf(pcnt[g], 1.0f);
    gs[t]       = psum[(size_t)g*EMB + t] * invc;
    gs[t + 128] = psum[(size_t)g*EMB + 128 + t] * invc;
    __syncthreads();
    float a = p1b[t];
    for (int k = 0; k < 256; ++k) a = fmaf(p1W[(size_t)t*256 + k], gs[k], a);
    h1[t] = fmaxf(a, 0.f);
    __syncthreads();
    float b = p2b[t];
    for (int k = 0; k < 128; ++k) b = fmaf(p2W[(size_t)t*128 + k], h1[k], b);
    h2[t] = fmaxf(b, 0.f);
    __syncthreads();
    float r = p3W[t] * h2[t];
    for (int off = 32; off > 0; off >>= 1) r += __shfl_down(r, off);
    if ((t & 63) == 0) red[t >> 6] = r;
    __syncthreads();
    if (t == 0) out[g] = red[0] + red[1] + p3b[0];
}

extern "C" void kernel_launch(void* const* d_in, const int* in_sizes, int n_in,
                              void* d_out, int out_size, void* d_ws, size_t ws_size,
                              hipStream_t stream)
{
    const float* x     = (const float*)d_in[0];
    const int*   eidx  = (const int*)d_in[1];
    const float* eattr = (const float*)d_in[2];
    const int*   batch = (const int*)d_in[3];
    const float* xW    = (const float*)d_in[4];
    const float* xb    = (const float*)d_in[5];
    const float* eW    = (const float*)d_in[6];
    const float* eb    = (const float*)d_in[7];
    const float* gcnW  = (const float*)d_in[8];
    const float* gcnb  = (const float*)d_in[9];
    const float* rootE = (const float*)d_in[10];
    const float* bng   = (const float*)d_in[11];
    const float* bnb   = (const float*)d_in[12];
    const float* p1W   = (const float*)d_in[13];
    const float* p1b   = (const float*)d_in[14];
    const float* p2W   = (const float*)d_in[15];
    const float* p2b   = (const float*)d_in[16];
    const float* p3W   = (const float*)d_in[17];
    const float* p3b   = (const float*)d_in[18];
    float* out = (float*)d_out;

    const int* row = eidx;
    const int* col = eidx + NE;

    const size_t HSZ = (size_t)NN * EMB;            // 25.6M elements

    // ws layout (bytes): agg f32 | h bf16 | hx bf16 | aux f32
    const size_t auxfloats = (size_t)NN*3 + NLAYERS*512 + 512 + (size_t)NG*EMB + NG;
    const size_t NEED = HSZ*4 + HSZ*2*2 + auxfloats*4;   // ~210.2 MB
    if (ws_size < NEED) return;   // fail absmax cleanly instead of faulting

    float* agg    = (float*)d_ws;                   // HSZ f32
    u16*   h      = (u16*)(agg + HSZ);              // HSZ bf16
    u16*   hx     = h + HSZ;                        // HSZ bf16
    float* degcnt = (float*)(hx + HSZ);
    float* dinv   = degcnt + NN;
    float* invdg  = dinv + NN;
    float* stats  = invdg + NN;                     // 5*512
    float* bnsc   = stats + NLAYERS*512;            // 512
    float* psum   = bnsc + 512;                     // NG*EMB
    float* pcnt   = psum + (size_t)NG*EMB;          // NG

    hipMemsetAsync(agg, 0, HSZ*sizeof(float), stream);
    hipMemsetAsync(degcnt, 0, auxfloats*sizeof(float), stream);

    embed_x<<<NN/XNB, 256, 0, stream>>>(x, xW, xb, h);
    deg_count<<<(NE+255)/256, 256, 0, stream>>>(row, degcnt, NE);
    deg_fin<<<(NN+255)/256, 256, 0, stream>>>(degcnt, dinv, invdg, NN);

    for (int l = 0; l < NLAYERS; ++l) {
        const float* Wl = gcnW + (size_t)l*EMB*EMB;
        const float* bl = gcnb + (size_t)l*EMB;
        const float* rl = rootE + (size_t)l*EMB;
        dim3 ggrid((NN+63)/64, EMB/64);
        gemm_hx<<<ggrid, 256, 0, stream>>>(h, Wl, bl, hx, NN);
        msg_kernel<<<NE/(4*EPW), 256, 0, stream>>>(row, col, eattr, eW, eb, dinv, hx, agg, NE);
        combine_kernel<<<1024, 256, 0, stream>>>(h, agg, hx, rl, invdg, stats + l*512, NN);
        bn_finalize<<<1, 256, 0, stream>>>(stats + l*512, bng + (size_t)l*EMB, bnb + (size_t)l*EMB, bnsc, NN);
        bn_apply<<<2048, 256, 0, stream>>>((const uint4*)hx, (uint4*)h, bnsc, (int)(HSZ/8), (l != NLAYERS-1) ? 1 : 0);
    }

    pool_kernel<<<(NN+255)/256, 256, 0, stream>>>(h, batch, psum, pcnt, NN);
    head_kernel<<<NG, 128, 0, stream>>>(psum, pcnt, p1W, p1b, p2W, p2b, p3W, p3b, out);
}

// Round 3
// 1470.680 us; speedup vs baseline: 1.9294x; 1.9294x over previous
//
#include <hip/hip_runtime.h>
#include <hip/hip_bf16.h>

#define NN 100000
#define NE 300000
#define NG 4096
#define EMB 256
#define NLAYERS 5

typedef unsigned short u16;
typedef unsigned int u32;

typedef short bf16x8 __attribute__((ext_vector_type(8)));
typedef float f32x4 __attribute__((ext_vector_type(4)));

__device__ __forceinline__ float b2f(u16 u){
    union { float f; u32 i; } v; v.i = ((u32)u) << 16; return v.f;
}
__device__ __forceinline__ u16 f2b(float f){
    __hip_bfloat16 h = __float2bfloat16(f);   // RNE
    union { __hip_bfloat16 h; u16 u; } v; v.h = h; return v.u;
}

// ---------------- x embedding: h = x @ xW.T + xb  (bf16 out) ----------------
#define XNB 32
__global__ __launch_bounds__(256) void embed_x(const float* __restrict__ x,
        const float* __restrict__ W, const float* __restrict__ b,
        u16* __restrict__ h)
{
    __shared__ float sW[256][41];
    __shared__ float sx[XNB][40];
    int tid = threadIdx.x;
    for (int i = tid; i < 256*40; i += 256) sW[i/40][i%40] = W[i];
    int n0 = blockIdx.x * XNB;      // 100000 = 3125*32 exact
    for (int i = tid; i < XNB*40; i += 256) {
        int j = i/40, k = i%40;
        sx[j][k] = x[(size_t)(n0+j)*40 + k];
    }
    __syncthreads();
    float bb = b[tid];
    for (int j = 0; j < XNB; ++j) {
        float a = bb;
        #pragma unroll
        for (int k = 0; k < 40; ++k) a = fmaf(sW[tid][k], sx[j][k], a);
        h[(size_t)(n0+j)*EMB + tid] = f2b(a);
    }
}

// ---------------- W -> bf16 ----------------
__global__ void wconv(const float* __restrict__ W, u16* __restrict__ Wb, int n)
{
    int i = blockIdx.x*256 + threadIdx.x;
    if (i < n) Wb[i] = f2b(W[i]);
}

// ---------------- histograms (row for degree, col for CSR) ----------------
__global__ void hist_kernel(const int* __restrict__ row, const int* __restrict__ col,
        int* __restrict__ rcnt, int* __restrict__ ccnt, int E)
{
    int e = blockIdx.x*256 + threadIdx.x;
    if (e < E) {
        atomicAdd(&rcnt[row[e]], 1);
        atomicAdd(&ccnt[col[e]], 1);
    }
}

__global__ void deg_fin(const int* __restrict__ rcnt, float* __restrict__ dinv,
                        float* __restrict__ invdg, int N)
{
    int n = blockIdx.x*256 + threadIdx.x;
    if (n < N) {
        float d = (float)rcnt[n] + 1.0f;
        dinv[n]  = rsqrtf(d);
        invdg[n] = 1.0f/d;
    }
}

// ---------------- prefix scan (3 kernels) ----------------
__global__ void scan1(const int* __restrict__ cnt, int* __restrict__ bsum, int N)
{
    __shared__ int sh[256];
    int t = threadIdx.x, i = blockIdx.x*256 + t;
    sh[t] = (i < N) ? cnt[i] : 0;
    __syncthreads();
    for (int off = 128; off > 0; off >>= 1) {
        if (t < off) sh[t] += sh[t+off];
        __syncthreads();
    }
    if (t == 0) bsum[blockIdx.x] = sh[0];
}

__global__ __launch_bounds__(512) void scan2(const int* __restrict__ bsum,
        int* __restrict__ bbase, int* __restrict__ coff, int nb)
{
    __shared__ int a[512], b[512];
    int t = threadIdx.x;
    a[t] = (t < nb) ? bsum[t] : 0;
    __syncthreads();
    int* src = a; int* dst = b;
    for (int off = 1; off < 512; off <<= 1) {
        dst[t] = (t >= off) ? src[t-off] + src[t] : src[t];
        __syncthreads();
        int* tmp = src; src = dst; dst = tmp;
    }
    bbase[t] = t ? src[t-1] : 0;
    if (t == 0) coff[NN] = NE;
}

__global__ void scan3(const int* __restrict__ cnt, const int* __restrict__ bbase,
        int* __restrict__ coff, int N)
{
    __shared__ int a[256], b[256];
    int t = threadIdx.x, i = blockIdx.x*256 + t;
    a[t] = (i < N) ? cnt[i] : 0;
    __syncthreads();
    int* src = a; int* dst = b;
    for (int off = 1; off < 256; off <<= 1) {
        dst[t] = (t >= off) ? src[t-off] + src[t] : src[t];
        __syncthreads();
        int* tmp = src; src = dst; dst = tmp;
    }
    if (i < N) coff[i] = bbase[blockIdx.x] + (t ? src[t-1] : 0);
}

__global__ void csr_fill(const int* __restrict__ col, const int* __restrict__ coff,
        int* __restrict__ fill, int* __restrict__ ceid, int E)
{
    int e = blockIdx.x*256 + threadIdx.x;
    if (e < E) {
        int c = col[e];
        int p = coff[c] + atomicAdd(&fill[c], 1);
        ceid[p] = e;
    }
}

// ---------------- MFMA GEMM: C[m][o] = sum_k A[m][k]*Wb[o][k] + bias[o] ----------------
// A,Wb,C bf16; f32 accum. 128x128 tile, 4 waves (2x2), BK=64, XOR-swizzled LDS.
#define BM 128
#define BK 64
__global__ __launch_bounds__(256) void gemm_mfma(const u16* __restrict__ A,
        const u16* __restrict__ Wb, const float* __restrict__ bias,
        u16* __restrict__ C, int M)
{
    __shared__ u16 As[BM*BK];   // chunk layout: 16B chunk idx = row*8 + (ch ^ (row&7))
    __shared__ u16 Bs[BM*BK];
    const int tid  = threadIdx.x;
    const int wid  = tid >> 6;
    const int lane = tid & 63;
    const int wr = wid >> 1, wc = wid & 1;       // 64x64 quadrant per wave
    const int m0 = blockIdx.x * BM;
    const int n0 = blockIdx.y * BM;
    f32x4 acc[4][4] = {};
    for (int k0 = 0; k0 < 256; k0 += BK) {
        #pragma unroll
        for (int i = 0; i < 4; ++i) {
            int L = tid + i*256;                 // 0..1023 chunk id
            int rowi = L >> 3, ch = L & 7;
            int sw = ch ^ (rowi & 7);
            int gr = m0 + rowi; gr = gr < M ? gr : M-1;
            uint4 va = *reinterpret_cast<const uint4*>(&A[(size_t)gr*256 + k0 + ch*8]);
            *reinterpret_cast<uint4*>(&As[(rowi*8 + sw)*8]) = va;
            uint4 vb = *reinterpret_cast<const uint4*>(&Wb[(size_t)(n0+rowi)*256 + k0 + ch*8]);
            *reinterpret_cast<uint4*>(&Bs[(rowi*8 + sw)*8]) = vb;
        }
        __syncthreads();
        const int c = lane >> 4;
        const int rl = lane & 15;
        #pragma unroll
        for (int kt = 0; kt < 2; ++kt) {
            bf16x8 af[4], bfr[4];
            #pragma unroll
            for (int f = 0; f < 4; ++f) {
                int ra = wr*64 + f*16 + rl;
                int cha = (kt*4 + c) ^ (ra & 7);
                af[f] = *reinterpret_cast<const bf16x8*>(&As[(ra*8 + cha)*8]);
                int rb = wc*64 + f*16 + rl;
                int chb = (kt*4 + c) ^ (rb & 7);
                bfr[f] = *reinterpret_cast<const bf16x8*>(&Bs[(rb*8 + chb)*8]);
            }
            #pragma unroll
            for (int fm = 0; fm < 4; ++fm)
                #pragma unroll
                for (int fn = 0; fn < 4; ++fn)
                    acc[fm][fn] = __builtin_amdgcn_mfma_f32_16x16x32_bf16(
                        af[fm], bfr[fn], acc[fm][fn], 0, 0, 0);
        }
        __syncthreads();
    }
    // epilogue: C/D layout col=lane&15, row=(lane>>4)*4+reg  [m89/m91]
    const int cn = lane & 15, rq = lane >> 4;
    #pragma unroll
    for (int fn = 0; fn < 4; ++fn) {
        int n = n0 + wc*64 + fn*16 + cn;
        float bb = bias[n];
        #pragma unroll
        for (int fm = 0; fm < 4; ++fm) {
            #pragma unroll
            for (int r = 0; r < 4; ++r) {
                int m = m0 + wr*64 + fm*16 + rq*4 + r;
                if (m < M) C[(size_t)m*256 + n] = f2b(acc[fm][fn][r] + bb);
            }
        }
    }
}

// ---------------- gather message pass (CSR by col), agg bf16 out ----------------
__global__ __launch_bounds__(256) void gather_msg(const int* __restrict__ ceid,
        const int* __restrict__ coff, const int* __restrict__ rowv,
        const float* __restrict__ eattr, const float* __restrict__ eW,
        const float* __restrict__ eb, const float* __restrict__ dinv,
        const u16* __restrict__ hx, u16* __restrict__ agg, int N)
{
    int n = blockIdx.x*4 + (threadIdx.x >> 6);
    int lane = threadIdx.x & 63;
    if (n >= N) return;
    // per-lane edge-MLP weights for features lane*4+j, hoisted to registers
    float w[4][10], bb[4];
    #pragma unroll
    for (int j = 0; j < 4; ++j) {
        int f = lane*4 + j;
        bb[j] = eb[f];
        #pragma unroll
        for (int k = 0; k < 10; ++k) w[j][k] = eW[f*10 + k];
    }
    float dn = dinv[n];
    float acc[4] = {0.f, 0.f, 0.f, 0.f};
    int s = coff[n], e = coff[n+1];
    for (int i = s; i < e; ++i) {
        int eid = ceid[i];
        int r = rowv[eid];
        float nrm = dn * dinv[r];
        float at[10];
        #pragma unroll
        for (int k = 0; k < 10; ++k) at[k] = eattr[(size_t)eid*10 + k];
        uint2 hv = *reinterpret_cast<const uint2*>(&hx[(size_t)r*EMB + lane*4]);
        float hf[4] = { b2f((u16)(hv.x & 0xffffu)), b2f((u16)(hv.x >> 16)),
                        b2f((u16)(hv.y & 0xffffu)), b2f((u16)(hv.y >> 16)) };
        #pragma unroll
        for (int j = 0; j < 4; ++j) {
            float ea = bb[j];
            #pragma unroll
            for (int k = 0; k < 10; ++k) ea = fmaf(at[k], w[j][k], ea);
            float v = hf[j] + ea;
            acc[j] += v > 0.f ? v*nrm : 0.f;
        }
    }
    uint2 o;
    o.x = (u32)f2b(acc[0]) | ((u32)f2b(acc[1]) << 16);
    o.y = (u32)f2b(acc[2]) | ((u32)f2b(acc[3]) << 16);
    *reinterpret_cast<uint2*>(&agg[(size_t)n*EMB + lane*4]) = o;
}

// ---------------- combine + BN stats ----------------
// t = h_in + agg + relu(hx+root)/deg -> hx (bf16); per-feature sums -> stats
__global__ __launch_bounds__(256) void combine_kernel(const u16* __restrict__ h,
        const u16* __restrict__ agg, u16* __restrict__ hx,
        const float* __restrict__ rootv, const float* __restrict__ invdeg,
        float* __restrict__ stats, int N)
{
    int t = threadIdx.x;
    int f4 = (t & 63) * 4;
    int sub = t >> 6;
    float4 root = *reinterpret_cast<const float4*>(&rootv[f4]);
    float s[4] = {0,0,0,0}, s2[4] = {0,0,0,0};
    for (int nb = blockIdx.x*4; nb < N; nb += gridDim.x*4) {
        int n = nb + sub;
        if (n < N) {
            size_t idx = (size_t)n*EMB + f4;
            uint2 av = *reinterpret_cast<const uint2*>(&agg[idx]);
            uint2 hv = *reinterpret_cast<const uint2*>(&h[idx]);
            uint2 xv = *reinterpret_cast<const uint2*>(&hx[idx]);
            float id = invdeg[n];
            float ag[4] = { b2f((u16)(av.x&0xffffu)), b2f((u16)(av.x>>16)),
                            b2f((u16)(av.y&0xffffu)), b2f((u16)(av.y>>16)) };
            float hh[4] = { b2f((u16)(hv.x&0xffffu)), b2f((u16)(hv.x>>16)),
                            b2f((u16)(hv.y&0xffffu)), b2f((u16)(hv.y>>16)) };
            float xx[4] = { b2f((u16)(xv.x&0xffffu)), b2f((u16)(xv.x>>16)),
                            b2f((u16)(xv.y&0xffffu)), b2f((u16)(xv.y>>16)) };
            float rt[4] = { root.x, root.y, root.z, root.w };
            u16 ov[4];
            #pragma unroll
            for (int j = 0; j < 4; ++j) {
                float hvj = xx[j] + rt[j];
                hvj = hvj > 0.f ? hvj : 0.f;
                float tv = hh[j] + ag[j] + hvj * id;
                ov[j] = f2b(tv);
                s[j] += tv;
                s2[j] += tv*tv;
            }
            uint2 o; o.x = (u32)ov[0] | ((u32)ov[1]<<16); o.y = (u32)ov[2] | ((u32)ov[3]<<16);
            *reinterpret_cast<uint2*>(&hx[idx]) = o;
        }
    }
    __shared__ float red[4][512];
    #pragma unroll
    for (int j = 0; j < 4; ++j) {
        red[sub][f4+j] = s[j];
        red[sub][256+f4+j] = s2[j];
    }
    __syncthreads();
    float a0 = red[0][t] + red[1][t] + red[2][t] + red[3][t];
    float a1 = red[0][256+t] + red[1][256+t] + red[2][256+t] + red[3][256+t];
    atomicAdd(&stats[t], a0);
    atomicAdd(&stats[256+t], a1);
}

// ---------------- BN finalize ----------------
__global__ void bn_finalize(const float* __restrict__ stats,
        const float* __restrict__ gamma, const float* __restrict__ beta,
        float* __restrict__ sc, int N)
{
    int f = threadIdx.x;
    float inv = 1.0f / (float)N;
    float mean = stats[f] * inv;
    float var  = stats[256+f] * inv - mean*mean;
    float is = rsqrtf(var + 1e-5f);
    float scale = gamma[f] * is;
    sc[f] = scale;
    sc[256+f] = fmaf(-mean, scale, beta[f]);
}

// ---------------- BN apply (+optional relu), bf16, 8 elems/thread ----------------
__global__ __launch_bounds__(256) void bn_apply(const uint4* __restrict__ t,
        uint4* __restrict__ h, const float* __restrict__ sc, int n8, int doRelu)
{
    size_t i0 = (size_t)blockIdx.x*blockDim.x + threadIdx.x;
    int f = (int)((i0*8) & 255);
    float s[8], sh[8];
    #pragma unroll
    for (int j = 0; j < 8; ++j) { s[j] = sc[f+j]; sh[j] = sc[256+f+j]; }
    size_t stride = (size_t)gridDim.x*blockDim.x;
    for (size_t i = i0; i < (size_t)n8; i += stride) {
        uint4 v = t[i];
        u32 w[4] = {v.x, v.y, v.z, v.w};
        u32 o[4];
        #pragma unroll
        for (int j = 0; j < 4; ++j) {
            float lo = b2f((u16)(w[j] & 0xffffu));
            float hi = b2f((u16)(w[j] >> 16));
            lo = fmaf(lo, s[2*j],   sh[2*j]);
            hi = fmaf(hi, s[2*j+1], sh[2*j+1]);
            if (doRelu) { lo = fmaxf(lo, 0.f); hi = fmaxf(hi, 0.f); }
            o[j] = (u32)f2b(lo) | ((u32)f2b(hi) << 16);
        }
        uint4 r; r.x = o[0]; r.y = o[1]; r.z = o[2]; r.w = o[3];
        h[i] = r;
    }
}

// ---------------- mean pool over sorted batch ----------------
__global__ __launch_bounds__(256) void pool_kernel(const u16* __restrict__ h,
        const int* __restrict__ batch, float* __restrict__ psum,
        float* __restrict__ pcnt, int N)
{
    int f = threadIdx.x;
    int n0 = blockIdx.x * 256;
    int n1 = min(n0 + 256, N);
    int cur = batch[n0];
    float acc = 0.f;
    int cnt = 0;
    for (int n = n0; n < n1; ++n) {
        int g = batch[n];                 // block-uniform (sorted)
        if (g != cur) {
            atomicAdd(&psum[(size_t)cur*EMB + f], acc);
            if (f == 0) atomicAdd(&pcnt[cur], (float)cnt);
            acc = 0.f; cnt = 0; cur = g;
        }
        acc += b2f(h[(size_t)n*EMB + f]);
        ++cnt;
    }
    atomicAdd(&psum[(size_t)cur*EMB + f], acc);
    if (f == 0) atomicAdd(&pcnt[cur], (float)cnt);
}

// ---------------- fused MLP head ----------------
__global__ __launch_bounds__(128) void head_kernel(const float* __restrict__ psum,
        const float* __restrict__ pcnt,
        const float* __restrict__ p1W, const float* __restrict__ p1b,
        const float* __restrict__ p2W, const float* __restrict__ p2b,
        const float* __restrict__ p3W, const float* __restrict__ p3b,
        float* __restrict__ out)
{
    __shared__ float gs[256];
    __shared__ float h1[128];
    __shared__ float h2[128];
    __shared__ float red[2];
    int g = blockIdx.x, t = threadIdx.x;
    float invc = 1.0f / fmaxf(pcnt[g], 1.0f);
    gs[t]       = psum[(size_t)g*EMB + t] * invc;
    gs[t + 128] = psum[(size_t)g*EMB + 128 + t] * invc;
    __syncthreads();
    float a = p1b[t];
    for (int k = 0; k < 256; ++k) a = fmaf(p1W[(size_t)t*256 + k], gs[k], a);
    h1[t] = fmaxf(a, 0.f);
    __syncthreads();
    float b = p2b[t];
    for (int k = 0; k < 128; ++k) b = fmaf(p2W[(size_t)t*128 + k], h1[k], b);
    h2[t] = fmaxf(b, 0.f);
    __syncthreads();
    float r = p3W[t] * h2[t];
    for (int off = 32; off > 0; off >>= 1) r += __shfl_down(r, off);
    if ((t & 63) == 0) red[t >> 6] = r;
    __syncthreads();
    if (t == 0) out[g] = red[0] + red[1] + p3b[0];
}

extern "C" void kernel_launch(void* const* d_in, const int* in_sizes, int n_in,
                              void* d_out, int out_size, void* d_ws, size_t ws_size,
                              hipStream_t stream)
{
    const float* x     = (const float*)d_in[0];
    const int*   eidx  = (const int*)d_in[1];
    const float* eattr = (const float*)d_in[2];
    const int*   batch = (const int*)d_in[3];
    const float* xW    = (const float*)d_in[4];
    const float* xb    = (const float*)d_in[5];
    const float* eW    = (const float*)d_in[6];
    const float* eb    = (const float*)d_in[7];
    const float* gcnW  = (const float*)d_in[8];
    const float* gcnb  = (const float*)d_in[9];
    const float* rootE = (const float*)d_in[10];
    const float* bng   = (const float*)d_in[11];
    const float* bnb   = (const float*)d_in[12];
    const float* p1W   = (const float*)d_in[13];
    const float* p1b   = (const float*)d_in[14];
    const float* p2W   = (const float*)d_in[15];
    const float* p2b   = (const float*)d_in[16];
    const float* p3W   = (const float*)d_in[17];
    const float* p3b   = (const float*)d_in[18];
    float* out = (float*)d_out;

    const int* row = eidx;
    const int* col = eidx + NE;

    const size_t HSZ = (size_t)NN * EMB;            // 25.6M elements
    const int NWB = 5*EMB*EMB;                      // 327680

    // ---- ws layout ----
    char* p = (char*)d_ws;
    u16* agg = (u16*)p;            p += HSZ*2;
    u16* h   = (u16*)p;            p += HSZ*2;
    u16* hx  = (u16*)p;            p += HSZ*2;
    u16* Wb  = (u16*)p;            p += (size_t)NWB*2;
    // zeroed accumulator region starts here
    char* zbase = p;
    int* rcnt   = (int*)p;         p += (size_t)NN*4;
    int* ccnt   = (int*)p;         p += (size_t)NN*4;
    int* fill   = (int*)p;         p += (size_t)NN*4;
    float* stats= (float*)p;       p += (size_t)NLAYERS*512*4;
    float* psum = (float*)p;       p += (size_t)NG*EMB*4;
    float* pcnt = (float*)p;       p += (size_t)NG*4;
    size_t zbytes = (size_t)(p - zbase);
    float* dinv = (float*)p;       p += (size_t)NN*4;
    float* invdg= (float*)p;       p += (size_t)NN*4;
    float* bnsc = (float*)p;       p += 512*4;
    int* coff   = (int*)p;         p += (size_t)(NN+1)*4;
    int* bsum   = (int*)p;         p += 512*4;
    int* bbase  = (int*)p;         p += 512*4;
    int* ceid   = (int*)p;         p += (size_t)NE*4;
    size_t NEED = (size_t)(p - (char*)d_ws);
    if (ws_size < NEED) return;    // fail absmax cleanly instead of faulting

    hipMemsetAsync(zbase, 0, zbytes, stream);

    const int NBS = (NN + 255)/256;   // 391 scan blocks

    embed_x<<<NN/XNB, 256, 0, stream>>>(x, xW, xb, h);
    wconv<<<(NWB+255)/256, 256, 0, stream>>>(gcnW, Wb, NWB);
    hist_kernel<<<(NE+255)/256, 256, 0, stream>>>(row, col, rcnt, ccnt, NE);
    deg_fin<<<NBS, 256, 0, stream>>>(rcnt, dinv, invdg, NN);
    scan1<<<NBS, 256, 0, stream>>>(ccnt, bsum, NN);
    scan2<<<1, 512, 0, stream>>>(bsum, bbase, coff, NBS);
    scan3<<<NBS, 256, 0, stream>>>(ccnt, bbase, coff, NN);
    csr_fill<<<(NE+255)/256, 256, 0, stream>>>(col, coff, fill, ceid, NE);

    for (int l = 0; l < NLAYERS; ++l) {
        const u16*   Wl = Wb + (size_t)l*EMB*EMB;
        const float* bl = gcnb + (size_t)l*EMB;
        const float* rl = rootE + (size_t)l*EMB;
        dim3 ggrid((NN + BM - 1)/BM, EMB/BM);
        gemm_mfma<<<ggrid, 256, 0, stream>>>(h, Wl, bl, hx, NN);
        gather_msg<<<(NN+3)/4, 256, 0, stream>>>(ceid, coff, row, eattr, eW, eb,
                                                 dinv, hx, agg, NN);
        combine_kernel<<<1024, 256, 0, stream>>>(h, agg, hx, rl, invdg,
                                                 stats + l*512, NN);
        bn_finalize<<<1, 256, 0, stream>>>(stats + l*512, bng + (size_t)l*EMB,
                                           bnb + (size_t)l*EMB, bnsc, NN);
        bn_apply<<<2048, 256, 0, stream>>>((const uint4*)hx, (uint4*)h, bnsc,
                                           (int)(HSZ/8), (l != NLAYERS-1) ? 1 : 0);
    }

    pool_kernel<<<NBS, 256, 0, stream>>>(h, batch, psum, pcnt, NN);
    head_kernel<<<NG, 128, 0, stream>>>(psum, pcnt, p1W, p1b, p2W, p2b, p3W, p3b, out);
}

// Round 4
// 1416.879 us; speedup vs baseline: 2.0027x; 1.0380x over previous
//
#include <hip/hip_runtime.h>
#include <hip/hip_bf16.h>

#define NN 100000
#define NE 300000
#define NG 4096
#define EMB 256
#define NLAYERS 5

typedef unsigned short u16;
typedef unsigned int u32;

typedef short bf16x8 __attribute__((ext_vector_type(8)));
typedef float f32x4 __attribute__((ext_vector_type(4)));

__device__ __forceinline__ float b2f(u16 u){
    union { float f; u32 i; } v; v.i = ((u32)u) << 16; return v.f;
}
__device__ __forceinline__ u16 f2b(float f){
    __hip_bfloat16 h = __float2bfloat16(f);   // RNE
    union { __hip_bfloat16 h; u16 u; } v; v.h = h; return v.u;
}

// ---------------- x embedding: h = x @ xW.T + xb  (bf16 out) ----------------
#define XNB 32
__global__ __launch_bounds__(256) void embed_x(const float* __restrict__ x,
        const float* __restrict__ W, const float* __restrict__ b,
        u16* __restrict__ h)
{
    __shared__ float sW[256][41];
    __shared__ float sx[XNB][40];
    int tid = threadIdx.x;
    for (int i = tid; i < 256*40; i += 256) sW[i/40][i%40] = W[i];
    int n0 = blockIdx.x * XNB;      // 100000 = 3125*32 exact
    for (int i = tid; i < XNB*40; i += 256) {
        int j = i/40, k = i%40;
        sx[j][k] = x[(size_t)(n0+j)*40 + k];
    }
    __syncthreads();
    float bb = b[tid];
    for (int j = 0; j < XNB; ++j) {
        float a = bb;
        #pragma unroll
        for (int k = 0; k < 40; ++k) a = fmaf(sW[tid][k], sx[j][k], a);
        h[(size_t)(n0+j)*EMB + tid] = f2b(a);
    }
}

// ---------------- W -> bf16 ----------------
__global__ void wconv(const float* __restrict__ W, u16* __restrict__ Wb, int n)
{
    int i = blockIdx.x*256 + threadIdx.x;
    if (i < n) Wb[i] = f2b(W[i]);
}

// ---------------- histograms (row for degree, col for CSR) ----------------
__global__ void hist_kernel(const int* __restrict__ row, const int* __restrict__ col,
        int* __restrict__ rcnt, int* __restrict__ ccnt, int E)
{
    int e = blockIdx.x*256 + threadIdx.x;
    if (e < E) {
        atomicAdd(&rcnt[row[e]], 1);
        atomicAdd(&ccnt[col[e]], 1);
    }
}

__global__ void deg_fin(const int* __restrict__ rcnt, float* __restrict__ dinv,
                        float* __restrict__ invdg, int N)
{
    int n = blockIdx.x*256 + threadIdx.x;
    if (n < N) {
        float d = (float)rcnt[n] + 1.0f;
        dinv[n]  = rsqrtf(d);
        invdg[n] = 1.0f/d;
    }
}

// ---------------- prefix scan (3 kernels) ----------------
__global__ void scan1(const int* __restrict__ cnt, int* __restrict__ bsum, int N)
{
    __shared__ int sh[256];
    int t = threadIdx.x, i = blockIdx.x*256 + t;
    sh[t] = (i < N) ? cnt[i] : 0;
    __syncthreads();
    for (int off = 128; off > 0; off >>= 1) {
        if (t < off) sh[t] += sh[t+off];
        __syncthreads();
    }
    if (t == 0) bsum[blockIdx.x] = sh[0];
}

__global__ __launch_bounds__(512) void scan2(const int* __restrict__ bsum,
        int* __restrict__ bbase, int* __restrict__ coff, int nb)
{
    __shared__ int a[512], b[512];
    int t = threadIdx.x;
    a[t] = (t < nb) ? bsum[t] : 0;
    __syncthreads();
    int* src = a; int* dst = b;
    for (int off = 1; off < 512; off <<= 1) {
        dst[t] = (t >= off) ? src[t-off] + src[t] : src[t];
        __syncthreads();
        int* tmp = src; src = dst; dst = tmp;
    }
    bbase[t] = t ? src[t-1] : 0;
    if (t == 0) coff[NN] = NE;
}

__global__ void scan3(const int* __restrict__ cnt, const int* __restrict__ bbase,
        int* __restrict__ coff, int N)
{
    __shared__ int a[256], b[256];
    int t = threadIdx.x, i = blockIdx.x*256 + t;
    a[t] = (i < N) ? cnt[i] : 0;
    __syncthreads();
    int* src = a; int* dst = b;
    for (int off = 1; off < 256; off <<= 1) {
        dst[t] = (t >= off) ? src[t-off] + src[t] : src[t];
        __syncthreads();
        int* tmp = src; src = dst; dst = tmp;
    }
    if (i < N) coff[i] = bbase[blockIdx.x] + (t ? src[t-1] : 0);
}

// CSR fill: materialize per-edge streams in CSR(col) order.
// erow[p] = row, enorm[p] = dinv[row]*dinv[col], ea10[p][10] = eattr[e][:]
__global__ void csr_fill(const int* __restrict__ row, const int* __restrict__ col,
        const float* __restrict__ eattr, const int* __restrict__ coff,
        const float* __restrict__ dinv, int* __restrict__ fill,
        int* __restrict__ erow, float* __restrict__ enorm,
        float* __restrict__ ea10, int E)
{
    int e = blockIdx.x*256 + threadIdx.x;
    if (e < E) {
        int c = col[e], r = row[e];
        int p = coff[c] + atomicAdd(&fill[c], 1);
        erow[p]  = r;
        enorm[p] = dinv[r] * dinv[c];
        #pragma unroll
        for (int k = 0; k < 10; ++k) ea10[(size_t)p*10 + k] = eattr[(size_t)e*10 + k];
    }
}

// ---------------- MFMA GEMM: C[m][o] = sum_k A[m][k]*Wb[o][k] + bias[o] ----------------
// A,Wb,C bf16; f32 accum. 128x128 tile, 4 waves (2x2), BK=64, XOR-swizzled LDS.
#define BM 128
#define BK 64
__global__ __launch_bounds__(256) void gemm_mfma(const u16* __restrict__ A,
        const u16* __restrict__ Wb, const float* __restrict__ bias,
        u16* __restrict__ C, int M)
{
    __shared__ u16 As[BM*BK];   // chunk layout: 16B chunk idx = row*8 + (ch ^ (row&7))
    __shared__ u16 Bs[BM*BK];
    const int tid  = threadIdx.x;
    const int wid  = tid >> 6;
    const int lane = tid & 63;
    const int wr = wid >> 1, wc = wid & 1;       // 64x64 quadrant per wave
    const int m0 = blockIdx.x * BM;
    const int n0 = blockIdx.y * BM;
    f32x4 acc[4][4] = {};
    for (int k0 = 0; k0 < 256; k0 += BK) {
        #pragma unroll
        for (int i = 0; i < 4; ++i) {
            int L = tid + i*256;                 // 0..1023 chunk id
            int rowi = L >> 3, ch = L & 7;
            int sw = ch ^ (rowi & 7);
            int gr = m0 + rowi; gr = gr < M ? gr : M-1;
            uint4 va = *reinterpret_cast<const uint4*>(&A[(size_t)gr*256 + k0 + ch*8]);
            *reinterpret_cast<uint4*>(&As[(rowi*8 + sw)*8]) = va;
            uint4 vb = *reinterpret_cast<const uint4*>(&Wb[(size_t)(n0+rowi)*256 + k0 + ch*8]);
            *reinterpret_cast<uint4*>(&Bs[(rowi*8 + sw)*8]) = vb;
        }
        __syncthreads();
        const int c = lane >> 4;
        const int rl = lane & 15;
        #pragma unroll
        for (int kt = 0; kt < 2; ++kt) {
            bf16x8 af[4], bfr[4];
            #pragma unroll
            for (int f = 0; f < 4; ++f) {
                int ra = wr*64 + f*16 + rl;
                int cha = (kt*4 + c) ^ (ra & 7);
                af[f] = *reinterpret_cast<const bf16x8*>(&As[(ra*8 + cha)*8]);
                int rb = wc*64 + f*16 + rl;
                int chb = (kt*4 + c) ^ (rb & 7);
                bfr[f] = *reinterpret_cast<const bf16x8*>(&Bs[(rb*8 + chb)*8]);
            }
            #pragma unroll
            for (int fm = 0; fm < 4; ++fm)
                #pragma unroll
                for (int fn = 0; fn < 4; ++fn)
                    acc[fm][fn] = __builtin_amdgcn_mfma_f32_16x16x32_bf16(
                        af[fm], bfr[fn], acc[fm][fn], 0, 0, 0);
        }
        __syncthreads();
    }
    // epilogue: C/D layout col=lane&15, row=(lane>>4)*4+reg  [m89/m91]
    const int cn = lane & 15, rq = lane >> 4;
    #pragma unroll
    for (int fn = 0; fn < 4; ++fn) {
        int n = n0 + wc*64 + fn*16 + cn;
        float bb = bias[n];
        #pragma unroll
        for (int fm = 0; fm < 4; ++fm) {
            #pragma unroll
            for (int r = 0; r < 4; ++r) {
                int m = m0 + wr*64 + fm*16 + rq*4 + r;
                if (m < M) C[(size_t)m*256 + n] = f2b(acc[fm][fn][r] + bb);
            }
        }
    }
}

// ---------------- gather message pass v2: 4 nodes per wave, CSR streams ----------------
#define GNPW 4
__global__ __launch_bounds__(256) void gather_msg(const int* __restrict__ erow,
        const float* __restrict__ enorm, const float* __restrict__ ea10,
        const int* __restrict__ coff,
        const float* __restrict__ eW, const float* __restrict__ eb,
        const float* __restrict__ dinv, const u16* __restrict__ hx,
        u16* __restrict__ agg, int N)
{
    int wid = threadIdx.x >> 6, lane = threadIdx.x & 63;
    int nb = (blockIdx.x*4 + wid) * GNPW;
    if (nb >= N) return;
    // per-lane edge-MLP weights for features lane*4+j
    float w[4][10], bb[4];
    #pragma unroll
    for (int j = 0; j < 4; ++j) {
        int f = lane*4 + j;
        bb[j] = eb[f];
        #pragma unroll
        for (int k = 0; k < 10; ++k) w[j][k] = eW[f*10 + k];
    }
    int idx[GNPW], end[GNPW];
    float acc[GNPW][4] = {};
    #pragma unroll
    for (int j = 0; j < GNPW; ++j) {
        int n = nb + j;
        idx[j] = (n < N) ? coff[n]   : 0;
        end[j] = (n < N) ? coff[n+1] : 0;
    }
    for (;;) {
        bool any = false;
        float nrm[GNPW];
        uint2 hv[GNPW];
        #pragma unroll
        for (int j = 0; j < GNPW; ++j) {
            if (idx[j] < end[j]) {
                any = true;
                int r = erow[idx[j]];
                nrm[j] = enorm[idx[j]];
                hv[j] = *reinterpret_cast<const uint2*>(&hx[(size_t)r*EMB + lane*4]);
            }
        }
        if (!any) break;
        #pragma unroll
        for (int j = 0; j < GNPW; ++j) {
            if (idx[j] < end[j]) {
                const float* at = &ea10[(size_t)idx[j]*10];
                float hf[4] = { b2f((u16)(hv[j].x & 0xffffu)), b2f((u16)(hv[j].x >> 16)),
                                b2f((u16)(hv[j].y & 0xffffu)), b2f((u16)(hv[j].y >> 16)) };
                #pragma unroll
                for (int jj = 0; jj < 4; ++jj) {
                    float ea = bb[jj];
                    #pragma unroll
                    for (int k = 0; k < 10; ++k) ea = fmaf(at[k], w[jj][k], ea);
                    float v = hf[jj] + ea;
                    acc[j][jj] += v > 0.f ? v*nrm[j] : 0.f;
                }
                idx[j]++;
            }
        }
    }
    #pragma unroll
    for (int j = 0; j < GNPW; ++j) {
        int n = nb + j;
        if (n < N) {
            uint2 o;
            o.x = (u32)f2b(acc[j][0]) | ((u32)f2b(acc[j][1]) << 16);
            o.y = (u32)f2b(acc[j][2]) | ((u32)f2b(acc[j][3]) << 16);
            *reinterpret_cast<uint2*>(&agg[(size_t)n*EMB + lane*4]) = o;
        }
    }
}

// ---------------- combine + BN stats ----------------
// t = h_in + agg + relu(hx+root)/deg -> hx (bf16); per-feature sums -> stats
__global__ __launch_bounds__(256) void combine_kernel(const u16* __restrict__ h,
        const u16* __restrict__ agg, u16* __restrict__ hx,
        const float* __restrict__ rootv, const float* __restrict__ invdeg,
        float* __restrict__ stats, int N)
{
    int t = threadIdx.x;
    int f4 = (t & 63) * 4;
    int sub = t >> 6;
    float4 root = *reinterpret_cast<const float4*>(&rootv[f4]);
    float s[4] = {0,0,0,0}, s2[4] = {0,0,0,0};
    for (int nb = blockIdx.x*4; nb < N; nb += gridDim.x*4) {
        int n = nb + sub;
        if (n < N) {
            size_t idx = (size_t)n*EMB + f4;
            uint2 av = *reinterpret_cast<const uint2*>(&agg[idx]);
            uint2 hv = *reinterpret_cast<const uint2*>(&h[idx]);
            uint2 xv = *reinterpret_cast<const uint2*>(&hx[idx]);
            float id = invdeg[n];
            float ag[4] = { b2f((u16)(av.x&0xffffu)), b2f((u16)(av.x>>16)),
                            b2f((u16)(av.y&0xffffu)), b2f((u16)(av.y>>16)) };
            float hh[4] = { b2f((u16)(hv.x&0xffffu)), b2f((u16)(hv.x>>16)),
                            b2f((u16)(hv.y&0xffffu)), b2f((u16)(hv.y>>16)) };
            float xx[4] = { b2f((u16)(xv.x&0xffffu)), b2f((u16)(xv.x>>16)),
                            b2f((u16)(xv.y&0xffffu)), b2f((u16)(xv.y>>16)) };
            float rt[4] = { root.x, root.y, root.z, root.w };
            u16 ov[4];
            #pragma unroll
            for (int j = 0; j < 4; ++j) {
                float hvj = xx[j] + rt[j];
                hvj = hvj > 0.f ? hvj : 0.f;
                float tv = hh[j] + ag[j] + hvj * id;
                ov[j] = f2b(tv);
                s[j] += tv;
                s2[j] += tv*tv;
            }
            uint2 o; o.x = (u32)ov[0] | ((u32)ov[1]<<16); o.y = (u32)ov[2] | ((u32)ov[3]<<16);
            *reinterpret_cast<uint2*>(&hx[idx]) = o;
        }
    }
    __shared__ float red[4][512];
    #pragma unroll
    for (int j = 0; j < 4; ++j) {
        red[sub][f4+j] = s[j];
        red[sub][256+f4+j] = s2[j];
    }
    __syncthreads();
    float a0 = red[0][t] + red[1][t] + red[2][t] + red[3][t];
    float a1 = red[0][256+t] + red[1][256+t] + red[2][256+t] + red[3][256+t];
    atomicAdd(&stats[t], a0);
    atomicAdd(&stats[256+t], a1);
}

// ---------------- BN finalize ----------------
__global__ void bn_finalize(const float* __restrict__ stats,
        const float* __restrict__ gamma, const float* __restrict__ beta,
        float* __restrict__ sc, int N)
{
    int f = threadIdx.x;
    float inv = 1.0f / (float)N;
    float mean = stats[f] * inv;
    float var  = stats[256+f] * inv - mean*mean;
    float is = rsqrtf(var + 1e-5f);
    float scale = gamma[f] * is;
    sc[f] = scale;
    sc[256+f] = fmaf(-mean, scale, beta[f]);
}

// ---------------- BN apply (+optional relu), bf16, 8 elems/thread ----------------
__global__ __launch_bounds__(256) void bn_apply(const uint4* __restrict__ t,
        uint4* __restrict__ h, const float* __restrict__ sc, int n8, int doRelu)
{
    size_t i0 = (size_t)blockIdx.x*blockDim.x + threadIdx.x;
    int f = (int)((i0*8) & 255);
    float s[8], sh[8];
    #pragma unroll
    for (int j = 0; j < 8; ++j) { s[j] = sc[f+j]; sh[j] = sc[256+f+j]; }
    size_t stride = (size_t)gridDim.x*blockDim.x;
    for (size_t i = i0; i < (size_t)n8; i += stride) {
        uint4 v = t[i];
        u32 w[4] = {v.x, v.y, v.z, v.w};
        u32 o[4];
        #pragma unroll
        for (int j = 0; j < 4; ++j) {
            float lo = b2f((u16)(w[j] & 0xffffu));
            float hi = b2f((u16)(w[j] >> 16));
            lo = fmaf(lo, s[2*j],   sh[2*j]);
            hi = fmaf(hi, s[2*j+1], sh[2*j+1]);
            if (doRelu) { lo = fmaxf(lo, 0.f); hi = fmaxf(hi, 0.f); }
            o[j] = (u32)f2b(lo) | ((u32)f2b(hi) << 16);
        }
        uint4 r; r.x = o[0]; r.y = o[1]; r.z = o[2]; r.w = o[3];
        h[i] = r;
    }
}

// ---------------- mean pool over sorted batch ----------------
__global__ __launch_bounds__(256) void pool_kernel(const u16* __restrict__ h,
        const int* __restrict__ batch, float* __restrict__ psum,
        float* __restrict__ pcnt, int N)
{
    int f = threadIdx.x;
    int n0 = blockIdx.x * 256;
    int n1 = min(n0 + 256, N);
    int cur = batch[n0];
    float acc = 0.f;
    int cnt = 0;
    for (int n = n0; n < n1; ++n) {
        int g = batch[n];                 // block-uniform (sorted)
        if (g != cur) {
            atomicAdd(&psum[(size_t)cur*EMB + f], acc);
            if (f == 0) atomicAdd(&pcnt[cur], (float)cnt);
            acc = 0.f; cnt = 0; cur = g;
        }
        acc += b2f(h[(size_t)n*EMB + f]);
        ++cnt;
    }
    atomicAdd(&psum[(size_t)cur*EMB + f], acc);
    if (f == 0) atomicAdd(&pcnt[cur], (float)cnt);
}

// ---------------- fused MLP head ----------------
__global__ __launch_bounds__(128) void head_kernel(const float* __restrict__ psum,
        const float* __restrict__ pcnt,
        const float* __restrict__ p1W, const float* __restrict__ p1b,
        const float* __restrict__ p2W, const float* __restrict__ p2b,
        const float* __restrict__ p3W, const float* __restrict__ p3b,
        float* __restrict__ out)
{
    __shared__ float gs[256];
    __shared__ float h1[128];
    __shared__ float h2[128];
    __shared__ float red[2];
    int g = blockIdx.x, t = threadIdx.x;
    float invc = 1.0f / fmaxf(pcnt[g], 1.0f);
    gs[t]       = psum[(size_t)g*EMB + t] * invc;
    gs[t + 128] = psum[(size_t)g*EMB + 128 + t] * invc;
    __syncthreads();
    float a = p1b[t];
    for (int k = 0; k < 256; ++k) a = fmaf(p1W[(size_t)t*256 + k], gs[k], a);
    h1[t] = fmaxf(a, 0.f);
    __syncthreads();
    float b = p2b[t];
    for (int k = 0; k < 128; ++k) b = fmaf(p2W[(size_t)t*128 + k], h1[k], b);
    h2[t] = fmaxf(b, 0.f);
    __syncthreads();
    float r = p3W[t] * h2[t];
    for (int off = 32; off > 0; off >>= 1) r += __shfl_down(r, off);
    if ((t & 63) == 0) red[t >> 6] = r;
    __syncthreads();
    if (t == 0) out[g] = red[0] + red[1] + p3b[0];
}

extern "C" void kernel_launch(void* const* d_in, const int* in_sizes, int n_in,
                              void* d_out, int out_size, void* d_ws, size_t ws_size,
                              hipStream_t stream)
{
    const float* x     = (const float*)d_in[0];
    const int*   eidx  = (const int*)d_in[1];
    const float* eattr = (const float*)d_in[2];
    const int*   batch = (const int*)d_in[3];
    const float* xW    = (const float*)d_in[4];
    const float* xb    = (const float*)d_in[5];
    const float* eW    = (const float*)d_in[6];
    const float* eb    = (const float*)d_in[7];
    const float* gcnW  = (const float*)d_in[8];
    const float* gcnb  = (const float*)d_in[9];
    const float* rootE = (const float*)d_in[10];
    const float* bng   = (const float*)d_in[11];
    const float* bnb   = (const float*)d_in[12];
    const float* p1W   = (const float*)d_in[13];
    const float* p1b   = (const float*)d_in[14];
    const float* p2W   = (const float*)d_in[15];
    const float* p2b   = (const float*)d_in[16];
    const float* p3W   = (const float*)d_in[17];
    const float* p3b   = (const float*)d_in[18];
    float* out = (float*)d_out;

    const int* row = eidx;
    const int* col = eidx + NE;

    const size_t HSZ = (size_t)NN * EMB;            // 25.6M elements
    const int NWB = 5*EMB*EMB;                      // 327680

    // ---- ws layout ----
    char* p = (char*)d_ws;
    u16* agg = (u16*)p;            p += HSZ*2;
    u16* h   = (u16*)p;            p += HSZ*2;
    u16* hx  = (u16*)p;            p += HSZ*2;
    u16* Wb  = (u16*)p;            p += (size_t)NWB*2;
    // zeroed accumulator region starts here
    char* zbase = p;
    int* rcnt   = (int*)p;         p += (size_t)NN*4;
    int* ccnt   = (int*)p;         p += (size_t)NN*4;
    int* fill   = (int*)p;         p += (size_t)NN*4;
    float* stats= (float*)p;       p += (size_t)NLAYERS*512*4;
    float* psum = (float*)p;       p += (size_t)NG*EMB*4;
    float* pcnt = (float*)p;       p += (size_t)NG*4;
    size_t zbytes = (size_t)(p - zbase);
    float* dinv = (float*)p;       p += (size_t)NN*4;
    float* invdg= (float*)p;       p += (size_t)NN*4;
    float* bnsc = (float*)p;       p += 512*4;
    int* coff   = (int*)p;         p += (size_t)(NN+1)*4;
    int* bsum   = (int*)p;         p += 512*4;
    int* bbase  = (int*)p;         p += 512*4;
    int* erow   = (int*)p;         p += (size_t)NE*4;
    float* enorm= (float*)p;       p += (size_t)NE*4;
    float* ea10 = (float*)p;       p += (size_t)NE*10*4;
    size_t NEED = (size_t)(p - (char*)d_ws);
    if (ws_size < NEED) return;    // fail absmax cleanly instead of faulting

    hipMemsetAsync(zbase, 0, zbytes, stream);

    const int NBS = (NN + 255)/256;   // 391 scan blocks

    embed_x<<<NN/XNB, 256, 0, stream>>>(x, xW, xb, h);
    wconv<<<(NWB+255)/256, 256, 0, stream>>>(gcnW, Wb, NWB);
    hist_kernel<<<(NE+255)/256, 256, 0, stream>>>(row, col, rcnt, ccnt, NE);
    deg_fin<<<NBS, 256, 0, stream>>>(rcnt, dinv, invdg, NN);
    scan1<<<NBS, 256, 0, stream>>>(ccnt, bsum, NN);
    scan2<<<1, 512, 0, stream>>>(bsum, bbase, coff, NBS);
    scan3<<<NBS, 256, 0, stream>>>(ccnt, bbase, coff, NN);
    csr_fill<<<(NE+255)/256, 256, 0, stream>>>(row, col, eattr, coff, dinv, fill,
                                               erow, enorm, ea10, NE);

    for (int l = 0; l < NLAYERS; ++l) {
        const u16*   Wl = Wb + (size_t)l*EMB*EMB;
        const float* bl = gcnb + (size_t)l*EMB;
        const float* rl = rootE + (size_t)l*EMB;
        dim3 ggrid((NN + BM - 1)/BM, EMB/BM);
        gemm_mfma<<<ggrid, 256, 0, stream>>>(h, Wl, bl, hx, NN);
        gather_msg<<<(NN + 4*GNPW - 1)/(4*GNPW), 256, 0, stream>>>(erow, enorm, ea10,
                                                 coff, eW, eb, dinv, hx, agg, NN);
        combine_kernel<<<1024, 256, 0, stream>>>(h, agg, hx, rl, invdg,
                                                 stats + l*512, NN);
        bn_finalize<<<1, 256, 0, stream>>>(stats + l*512, bng + (size_t)l*EMB,
                                           bnb + (size_t)l*EMB, bnsc, NN);
        bn_apply<<<2048, 256, 0, stream>>>((const uint4*)hx, (uint4*)h, bnsc,
                                           (int)(HSZ/8), (l != NLAYERS-1) ? 1 : 0);
    }

    pool_kernel<<<NBS, 256, 0, stream>>>(h, batch, psum, pcnt, NN);
    head_kernel<<<NG, 128, 0, stream>>>(psum, pcnt, p1W, p1b, p2W, p2b, p3W, p3b, out);
}